// Round 30
// baseline (33.697 us; speedup 1.0000x reference)
//
#include <hip/hip_runtime.h>

// MLP 30->24->19->14->10->6->2->1 via MFMA (v_mfma_f32_32x32x16_f16).
// R30 = R25 (shuffle-free, 29.8us best) + TWO INDEPENDENT CHAINS PER WAVE.
// Mechanism: all wave-level/prefetch-depth levers failed (R24/R27/R28);
// the untried axis is intra-wave ILP. Each loop iteration computes a PAIR
// of tiles with two interleaved independent 10-MFMA chains (~1400 cyc of
// compute, matching loaded HBM latency), with the pair's 8 dwordx4 issued
// at iteration start (q regs reused after B-frag build -- no R27-style
// copy churn). Waves stay at 16/CU (grid 1024, (256,4)).
// Kept exactly (proven): k-permuted A-staging (B-frag = straight cvt of
// own D-regs, zero cross-lane), bias at D-reg slot of feature FIN,
// per-lane direct x loads (4x float4), A-frags hoisted, 1 barrier.
// Layouts verified R19-R26 (absmax 1.95e-3).

#define NTHREADS 256
#define TPW 8                  // tiles per wave, processed as 4 pairs

typedef __fp16       h2     __attribute__((ext_vector_type(2)));
typedef __fp16       half8  __attribute__((ext_vector_type(8)));
typedef float        f32x16 __attribute__((ext_vector_type(16)));
typedef unsigned int uint4v __attribute__((ext_vector_type(4)));

__device__ __forceinline__ h2 cpk(float a, float b) {
    return __builtin_bit_cast(h2, __builtin_amdgcn_cvt_pkrtz(a, b));
}
__device__ __forceinline__ h2 relu2(h2 v) {
    h2 z = {(__fp16)0.f, (__fp16)0.f};
#if __has_builtin(__builtin_elementwise_max)
    return __builtin_elementwise_max(v, z);
#else
    v.x = v.x > (__fp16)0.f ? v.x : (__fp16)0.f;
    v.y = v.y > (__fp16)0.f ? v.y : (__fp16)0.f;
    return v;
#endif
}
__device__ __forceinline__ unsigned ucast(h2 v) { return __builtin_bit_cast(unsigned, v); }

__device__ __forceinline__ f32x16 mfma_(half8 A, half8 B, f32x16 C) {
    return __builtin_amdgcn_mfma_f32_32x32x16_f16(A, B, C, 0, 0, 0);
}

__device__ __forceinline__ float4 ldg4(const float* p) {
    float4 v;
    __builtin_memcpy(&v, p, 16);
    return v;
}

// ---- weight staging. PERM: source feature f = 16b + phi(c), phi =
// (c&3)+8*((c>>2)&1)+4*(c>>3), so next layer's B-frag needs no swap. ----
template <int FIN, int FOUT, int KPAD, bool PERM>
__device__ __forceinline__ void stageW(const float* __restrict__ W, const float* __restrict__ B,
                                       __fp16* __restrict__ sbase, int t) {
    for (int idx = t; idx < 32 * KPAD; idx += NTHREADS) {
        int m = idx / KPAD;
        int k = idx & (KPAD - 1);
        int f;
        if (PERM) {
            int c = k & 15;
            f = (k & ~15) + ((c & 3) + 8 * ((c >> 2) & 1) + 4 * ((c >> 3) & 1));
        } else {
            f = k;
        }
        float v = 0.f;
        if (m < FOUT) {
            if (f < FIN) v = W[m * FIN + f];
            else if (f == FIN) v = B[m];
        }
        int byte = idx * 2;
        byte ^= (m & 7) << 4;
        *(__fp16*)((char*)sbase + byte) = (__fp16)v;
    }
}

// A-fragment read: lane holds A'[m=lane&31][k = ks*16 + 8*(lane>>5) + j]
__device__ __forceinline__ half8 ldA(const __fp16* base, int KPAD, int ks, int lane) {
    int m = lane & 31;
    int byte = (m * KPAD + ks * 16 + ((lane >> 5) & 1) * 8) * 2;
    byte ^= (m & 7) << 4;
    return __builtin_bit_cast(half8, *(const uint4v*)((const char*)base + byte));
}

// B-fragment, NO shuffles: straight cvt of lane's own D-regs R..R+7.
// BW = word for bias 1.0 (-1 none), BODD = element, BHB = which lane half.
template <int R, int BW, int BODD, int BHB>
__device__ __forceinline__ half8 bfragn(const f32x16& d, int hb) {
    unsigned w0 = ucast(relu2(cpk(d[R + 0], d[R + 1])));
    unsigned w1 = ucast(relu2(cpk(d[R + 2], d[R + 3])));
    unsigned w2 = ucast(relu2(cpk(d[R + 4], d[R + 5])));
    unsigned w3 = ucast(relu2(cpk(d[R + 6], d[R + 7])));
    if constexpr (BW >= 0) {
        constexpr unsigned bits = BODD ? 0x3C000000u : 0x00003C00u;  // f16 1.0
        unsigned ob = (hb == BHB) ? bits : 0u;
        if constexpr (BW == 0) w0 |= ob;
        else if constexpr (BW == 1) w1 |= ob;
        else if constexpr (BW == 2) w2 |= ob;
        else w3 |= ob;
    }
    uint4v u = {w0, w1, w2, w3};
    return __builtin_bit_cast(half8, u);
}

__device__ __forceinline__ half8 packx(unsigned a, unsigned b, unsigned c, unsigned d) {
    uint4v u = {a, b, c, d};
    return __builtin_bit_cast(half8, u);
}

// layer-1 B-frags from a tile's 4 q regs (natural k order + bias @ k30)
__device__ __forceinline__ void l1frags(float4 q0, float4 q1, float4 q2, float4 q3,
                                        int hb, half8& Bx0, half8& Bx1) {
    Bx0 = packx(ucast(cpk(q0.x, q0.y)), ucast(cpk(q0.z, q0.w)),
                ucast(cpk(q1.x, q1.y)), ucast(cpk(q1.z, q1.w)));
    unsigned w2 = hb ? ucast(cpk(q3.z, q3.w))    // k28,29
                     : ucast(cpk(q3.x, q3.y));   // k20,21
    unsigned w3 = hb ? 0x00003C00u               // k30=1.0 (bias), k31=0
                     : ucast(cpk(q3.z, q3.w));   // k22,23
    Bx1 = packx(ucast(cpk(q2.x, q2.y)), ucast(cpk(q2.z, q2.w)), w2, w3);
}

__global__ __launch_bounds__(NTHREADS, 4) void mlp_mfma10(
    const float* __restrict__ x,
    const float* __restrict__ W1, const float* __restrict__ B1,
    const float* __restrict__ W2, const float* __restrict__ B2,
    const float* __restrict__ W3, const float* __restrict__ B3,
    const float* __restrict__ W4, const float* __restrict__ B4,
    const float* __restrict__ W5, const float* __restrict__ B5,
    const float* __restrict__ W6, const float* __restrict__ B6,
    const float* __restrict__ W7, const float* __restrict__ B7,
    float* __restrict__ out, int nrows)
{
    __shared__ __align__(16) __fp16 shw[5120];        // weights only, 10.2 KB

    const int t    = threadIdx.x;
    const int lane = t & 63;
    const int wid  = t >> 6;
    const int hb   = (lane >> 5) & 1;

    stageW<30, 24, 32, false>(W1, B1, shw + 0,    t);  // L1: identity
    stageW<24, 19, 32, true >(W2, B2, shw + 1024, t);
    stageW<19, 14, 32, true >(W3, B3, shw + 2048, t);
    stageW<14, 10, 16, true >(W4, B4, shw + 3072, t);
    stageW<10, 6,  16, true >(W5, B5, shw + 3584, t);
    stageW<6,  2,  16, true >(W6, B6, shw + 4096, t);
    stageW<2,  1,  16, true >(W7, B7, shw + 4608, t);
    __syncthreads();                                  // the ONLY barrier

    // ---- hoist all A-fragments into registers (10 x 4 VGPR) ----
    const half8 A10 = ldA(shw + 0,    32, 0, lane), A11 = ldA(shw + 0,    32, 1, lane);
    const half8 A20 = ldA(shw + 1024, 32, 0, lane), A21 = ldA(shw + 1024, 32, 1, lane);
    const half8 A30 = ldA(shw + 2048, 32, 0, lane), A31 = ldA(shw + 2048, 32, 1, lane);
    const half8 A4  = ldA(shw + 3072, 16, 0, lane);
    const half8 A5  = ldA(shw + 3584, 16, 0, lane);
    const half8 A6  = ldA(shw + 4096, 16, 0, lane);
    const half8 A7  = ldA(shw + 4608, 16, 0, lane);

    const f32x16 z = {0.f,0.f,0.f,0.f, 0.f,0.f,0.f,0.f, 0.f,0.f,0.f,0.f, 0.f,0.f,0.f,0.f};

    const int tile0 = (blockIdx.x * 4 + wid) * TPW;
    const int myrow = lane & 31;
    const int off0  = hb * 8;
    const int off1  = 16 + hb * 8;
    const int off3  = 20 + hb * 6;       // 20..23 (lo) / 26..29 (hi, .z.w used)

    // prefetch pair 0 (tiles 0,1)
    float4 qA0, qA1, qA2, qA3, qB0, qB1, qB2, qB3;
    {
        const float* a = x + ((size_t)(tile0 * 32 + myrow)) * 30;
        qA0 = ldg4(a + off0); qA1 = ldg4(a + off0 + 4);
        qA2 = ldg4(a + off1); qA3 = ldg4(a + off3);
        const float* b = a + 32 * 30;
        qB0 = ldg4(b + off0); qB1 = ldg4(b + off0 + 4);
        qB2 = ldg4(b + off1); qB3 = ldg4(b + off3);
    }

#pragma unroll
    for (int it = 0; it < TPW; it += 2) {
        const int TA = tile0 + it, TB = TA + 1;

        // ---- build both tiles' layer-1 B-frags (frees q regs) ----
        half8 BxA0, BxA1, BxB0, BxB1;
        l1frags(qA0, qA1, qA2, qA3, hb, BxA0, BxA1);
        l1frags(qB0, qB1, qB2, qB3, hb, BxB0, BxB1);

        // ---- issue next pair's loads into the reused q regs ----
        if (it + 2 < TPW) {
            const float* a = x + ((size_t)((TA + 2) * 32 + myrow)) * 30;
            qA0 = ldg4(a + off0); qA1 = ldg4(a + off0 + 4);
            qA2 = ldg4(a + off1); qA3 = ldg4(a + off3);
            const float* b = a + 32 * 30;
            qB0 = ldg4(b + off0); qB1 = ldg4(b + off0 + 4);
            qB2 = ldg4(b + off1); qB3 = ldg4(b + off3);
        }

        // ---- two independent 10-MFMA chains, interleaved ----
        f32x16 a1 = mfma_(A10, BxA0, z);
        f32x16 b1 = mfma_(A10, BxB0, z);
        a1 = mfma_(A11, BxA1, a1);
        b1 = mfma_(A11, BxB1, b1);
        f32x16 a2 = mfma_(A20, bfragn<0, -1, 0, 0>(a1, hb), z);
        f32x16 b2 = mfma_(A20, bfragn<0, -1, 0, 0>(b1, hb), z);
        a2 = mfma_(A21, bfragn<8, 2, 0, 0>(a1, hb), a2);
        b2 = mfma_(A21, bfragn<8, 2, 0, 0>(b1, hb), b2);
        f32x16 a3 = mfma_(A30, bfragn<0, -1, 0, 0>(a2, hb), z);
        f32x16 b3 = mfma_(A30, bfragn<0, -1, 0, 0>(b2, hb), z);
        a3 = mfma_(A31, bfragn<8, 1, 1, 0>(a2, hb), a3);
        b3 = mfma_(A31, bfragn<8, 1, 1, 0>(b2, hb), b3);
        f32x16 a4 = mfma_(A4, bfragn<0, 3, 0, 1>(a3, hb), z);
        f32x16 b4 = mfma_(A4, bfragn<0, 3, 0, 1>(b3, hb), z);
        f32x16 a5 = mfma_(A5, bfragn<0, 3, 0, 0>(a4, hb), z);
        f32x16 b5 = mfma_(A5, bfragn<0, 3, 0, 0>(b4, hb), z);
        f32x16 a6 = mfma_(A6, bfragn<0, 1, 0, 1>(a5, hb), z);
        f32x16 b6 = mfma_(A6, bfragn<0, 1, 0, 1>(b5, hb), z);
        f32x16 a7 = mfma_(A7, bfragn<0, 1, 0, 0>(a6, hb), z);
        f32x16 b7 = mfma_(A7, bfragn<0, 1, 0, 0>(b6, hb), z);

        if (lane < 32) {
            int rA = TA * 32 + lane;
            int rB = TB * 32 + lane;
            if (rA < nrows) out[rA] = a7[0];
            if (rB < nrows) out[rB] = b7[0];
        }
    }
}

extern "C" void kernel_launch(void* const* d_in, const int* in_sizes, int n_in,
                              void* d_out, int out_size, void* d_ws, size_t ws_size,
                              hipStream_t stream) {
    const float* x = (const float*)d_in[0];
    int nrows = in_sizes[0] / 30;
    int rows_per_block = 4 * TPW * 32;                // 1024
    int blocks = (nrows + rows_per_block - 1) / rows_per_block;   // 1024
    mlp_mfma10<<<blocks, NTHREADS, 0, stream>>>(
        x,
        (const float*)d_in[1],  (const float*)d_in[2],
        (const float*)d_in[3],  (const float*)d_in[4],
        (const float*)d_in[5],  (const float*)d_in[6],
        (const float*)d_in[7],  (const float*)d_in[8],
        (const float*)d_in[9],  (const float*)d_in[10],
        (const float*)d_in[11], (const float*)d_in[12],
        (const float*)d_in[13], (const float*)d_in[14],
        (float*)d_out, nrows);
}

// Round 31
// 29.589 us; speedup vs baseline: 1.1388x; 1.1388x over previous
//
#include <hip/hip_runtime.h>

// MLP 30->24->19->14->10->6->2->1 via MFMA (v_mfma_f32_32x32x16_f16).
// FINAL (= R25, session best 29.8us). Six latency/overlap levers probed
// and rejected: depth-2 prefetch (R24 neutral, R27 regression), occupancy
// (256,5)+TPW4 (R29 regression), barrier-free restructure (R21 neutral),
// dual independent chains (R30 regression). Ceiling model: HBM 130MB
// ~20.6us (half L3-absorbed) overlapped with ~8us structural TA
// line-transaction cost of per-lane row-sliced loads (the price of the
// zero-shuffle MFMA B-feed; coalesced alternatives measured worse) and
// ~4us issue -> ~29us, matching measurement.
// Structure:
//  - k-permuted A-staging: A'[m][16b+c] = W[m][16b+phi(c)],
//    phi(c)=(c&3)+8*((c>>2)&1)+4*(c>>3) -> B-frag = straight cvt_pkrtz of
//    the lane's own 8 D-regs, ZERO cross-lane ops (R25 win, +5%).
//  - bias folded as extra K-slot, injected at D-reg slot of feature FIN.
//  - per-lane direct x loads (4x float4, 1-tile prefetch under MFMA chain).
//  - all 10 A-frags hoisted to registers; weights f16 in LDS (10.2 KB);
//    one barrier total; TPW=8, grid 1024, __launch_bounds__(256,4).
// Layouts verified R19-R26 (absmax 1.95e-3 = harness bf16 rounding floor).

#define NTHREADS 256
#define TPW 8

typedef __fp16       h2     __attribute__((ext_vector_type(2)));
typedef __fp16       half8  __attribute__((ext_vector_type(8)));
typedef float        f32x16 __attribute__((ext_vector_type(16)));
typedef unsigned int uint4v __attribute__((ext_vector_type(4)));

__device__ __forceinline__ h2 cpk(float a, float b) {
    return __builtin_bit_cast(h2, __builtin_amdgcn_cvt_pkrtz(a, b));
}
__device__ __forceinline__ h2 relu2(h2 v) {
    h2 z = {(__fp16)0.f, (__fp16)0.f};
#if __has_builtin(__builtin_elementwise_max)
    return __builtin_elementwise_max(v, z);
#else
    v.x = v.x > (__fp16)0.f ? v.x : (__fp16)0.f;
    v.y = v.y > (__fp16)0.f ? v.y : (__fp16)0.f;
    return v;
#endif
}
__device__ __forceinline__ unsigned ucast(h2 v) { return __builtin_bit_cast(unsigned, v); }

__device__ __forceinline__ f32x16 mfma_(half8 A, half8 B, f32x16 C) {
    return __builtin_amdgcn_mfma_f32_32x32x16_f16(A, B, C, 0, 0, 0);
}

__device__ __forceinline__ float4 ldg4(const float* p) {
    float4 v;
    __builtin_memcpy(&v, p, 16);
    return v;
}

// ---- weight staging. PERM: source feature f = 16b + phi(c), phi =
// (c&3)+8*((c>>2)&1)+4*(c>>3), so next layer's B-frag needs no swap. ----
template <int FIN, int FOUT, int KPAD, bool PERM>
__device__ __forceinline__ void stageW(const float* __restrict__ W, const float* __restrict__ B,
                                       __fp16* __restrict__ sbase, int t) {
    for (int idx = t; idx < 32 * KPAD; idx += NTHREADS) {
        int m = idx / KPAD;
        int k = idx & (KPAD - 1);
        int f;
        if (PERM) {
            int c = k & 15;
            f = (k & ~15) + ((c & 3) + 8 * ((c >> 2) & 1) + 4 * ((c >> 3) & 1));
        } else {
            f = k;
        }
        float v = 0.f;
        if (m < FOUT) {
            if (f < FIN) v = W[m * FIN + f];
            else if (f == FIN) v = B[m];
        }
        int byte = idx * 2;
        byte ^= (m & 7) << 4;
        *(__fp16*)((char*)sbase + byte) = (__fp16)v;
    }
}

// A-fragment read: lane holds A'[m=lane&31][k = ks*16 + 8*(lane>>5) + j]
__device__ __forceinline__ half8 ldA(const __fp16* base, int KPAD, int ks, int lane) {
    int m = lane & 31;
    int byte = (m * KPAD + ks * 16 + ((lane >> 5) & 1) * 8) * 2;
    byte ^= (m & 7) << 4;
    return __builtin_bit_cast(half8, *(const uint4v*)((const char*)base + byte));
}

// B-fragment, NO shuffles: straight cvt of lane's own D-regs R..R+7.
// BW = word for bias 1.0 (-1 none), BODD = element, BHB = which lane half.
template <int R, int BW, int BODD, int BHB>
__device__ __forceinline__ half8 bfragn(const f32x16& d, int hb) {
    unsigned w0 = ucast(relu2(cpk(d[R + 0], d[R + 1])));
    unsigned w1 = ucast(relu2(cpk(d[R + 2], d[R + 3])));
    unsigned w2 = ucast(relu2(cpk(d[R + 4], d[R + 5])));
    unsigned w3 = ucast(relu2(cpk(d[R + 6], d[R + 7])));
    if constexpr (BW >= 0) {
        constexpr unsigned bits = BODD ? 0x3C000000u : 0x00003C00u;  // f16 1.0
        unsigned ob = (hb == BHB) ? bits : 0u;
        if constexpr (BW == 0) w0 |= ob;
        else if constexpr (BW == 1) w1 |= ob;
        else if constexpr (BW == 2) w2 |= ob;
        else w3 |= ob;
    }
    uint4v u = {w0, w1, w2, w3};
    return __builtin_bit_cast(half8, u);
}

__device__ __forceinline__ half8 packx(unsigned a, unsigned b, unsigned c, unsigned d) {
    uint4v u = {a, b, c, d};
    return __builtin_bit_cast(half8, u);
}

__global__ __launch_bounds__(NTHREADS, 4) void mlp_mfma_final(
    const float* __restrict__ x,
    const float* __restrict__ W1, const float* __restrict__ B1,
    const float* __restrict__ W2, const float* __restrict__ B2,
    const float* __restrict__ W3, const float* __restrict__ B3,
    const float* __restrict__ W4, const float* __restrict__ B4,
    const float* __restrict__ W5, const float* __restrict__ B5,
    const float* __restrict__ W6, const float* __restrict__ B6,
    const float* __restrict__ W7, const float* __restrict__ B7,
    float* __restrict__ out, int nrows)
{
    __shared__ __align__(16) __fp16 shw[5120];        // weights only, 10.2 KB

    const int t    = threadIdx.x;
    const int lane = t & 63;
    const int wid  = t >> 6;
    const int hb   = (lane >> 5) & 1;

    stageW<30, 24, 32, false>(W1, B1, shw + 0,    t);  // L1: identity
    stageW<24, 19, 32, true >(W2, B2, shw + 1024, t);
    stageW<19, 14, 32, true >(W3, B3, shw + 2048, t);
    stageW<14, 10, 16, true >(W4, B4, shw + 3072, t);
    stageW<10, 6,  16, true >(W5, B5, shw + 3584, t);
    stageW<6,  2,  16, true >(W6, B6, shw + 4096, t);
    stageW<2,  1,  16, true >(W7, B7, shw + 4608, t);
    __syncthreads();                                  // the ONLY barrier

    // ---- hoist all A-fragments into registers (10 x 4 VGPR) ----
    const half8 A10 = ldA(shw + 0,    32, 0, lane), A11 = ldA(shw + 0,    32, 1, lane);
    const half8 A20 = ldA(shw + 1024, 32, 0, lane), A21 = ldA(shw + 1024, 32, 1, lane);
    const half8 A30 = ldA(shw + 2048, 32, 0, lane), A31 = ldA(shw + 2048, 32, 1, lane);
    const half8 A4  = ldA(shw + 3072, 16, 0, lane);
    const half8 A5  = ldA(shw + 3584, 16, 0, lane);
    const half8 A6  = ldA(shw + 4096, 16, 0, lane);
    const half8 A7  = ldA(shw + 4608, 16, 0, lane);

    const f32x16 z = {0.f,0.f,0.f,0.f, 0.f,0.f,0.f,0.f, 0.f,0.f,0.f,0.f, 0.f,0.f,0.f,0.f};

    const int tile0 = (blockIdx.x * 4 + wid) * TPW;
    const int myrow = lane & 31;
    const int off0  = hb * 8;
    const int off1  = 16 + hb * 8;
    const int off3  = 20 + hb * 6;       // 20..23 (lo) / 26..29 (hi, .z.w used)

    float4 q0, q1, q2, q3;
    {
        const float* b = x + ((size_t)(tile0 * 32 + myrow)) * 30;
        q0 = ldg4(b + off0);
        q1 = ldg4(b + off0 + 4);
        q2 = ldg4(b + off1);
        q3 = ldg4(b + off3);
    }

    for (int it = 0; it < TPW; ++it) {
        const int T = tile0 + it;

        // ---- layer-1 B-frags from prefetch regs (natural k order) ----
        half8 Bx0 = packx(ucast(cpk(q0.x, q0.y)), ucast(cpk(q0.z, q0.w)),
                          ucast(cpk(q1.x, q1.y)), ucast(cpk(q1.z, q1.w)));
        unsigned w2 = hb ? ucast(cpk(q3.z, q3.w))    // k28,29
                         : ucast(cpk(q3.x, q3.y));   // k20,21
        unsigned w3 = hb ? 0x00003C00u               // k30=1.0 (bias), k31=0
                         : ucast(cpk(q3.z, q3.w));   // k22,23
        half8 Bx1 = packx(ucast(cpk(q2.x, q2.y)), ucast(cpk(q2.z, q2.w)), w2, w3);

        // ---- issue next tile's loads (hide under MFMA chain) ----
        if (it + 1 < TPW) {
            const float* b = x + ((size_t)((T + 1) * 32 + myrow)) * 30;
            q0 = ldg4(b + off0);
            q1 = ldg4(b + off0 + 4);
            q2 = ldg4(b + off1);
            q3 = ldg4(b + off3);
        }

        // ---- 10-MFMA chain, shuffle-free transitions ----
        f32x16 a1 = mfma_(A10, Bx0, z);
        a1 = mfma_(A11, Bx1, a1);
        // L2: bias feat 24 -> block1 word2, even, lo
        f32x16 a2 = mfma_(A20, bfragn<0, -1, 0, 0>(a1, hb), z);
        a2 = mfma_(A21, bfragn<8, 2, 0, 0>(a1, hb), a2);
        // L3: bias feat 19 -> block1 word1, odd, lo
        f32x16 a3 = mfma_(A30, bfragn<0, -1, 0, 0>(a2, hb), z);
        a3 = mfma_(A31, bfragn<8, 1, 1, 0>(a2, hb), a3);
        // L4: bias feat 14 -> word3, even, hi
        f32x16 a4 = mfma_(A4, bfragn<0, 3, 0, 1>(a3, hb), z);
        // L5: bias feat 10 -> word3, even, lo
        f32x16 a5 = mfma_(A5, bfragn<0, 3, 0, 0>(a4, hb), z);
        // L6: bias feat 6 -> word1, even, hi
        f32x16 a6 = mfma_(A6, bfragn<0, 1, 0, 1>(a5, hb), z);
        // L7: bias feat 2 -> word1, even, lo
        f32x16 a7 = mfma_(A7, bfragn<0, 1, 0, 0>(a6, hb), z);

        const int row0 = T * 32;
        if (lane < 32) {
            int r = row0 + lane;
            if (r < nrows) out[r] = a7[0];
        }
    }
}

extern "C" void kernel_launch(void* const* d_in, const int* in_sizes, int n_in,
                              void* d_out, int out_size, void* d_ws, size_t ws_size,
                              hipStream_t stream) {
    const float* x = (const float*)d_in[0];
    int nrows = in_sizes[0] / 30;
    int rows_per_block = 4 * TPW * 32;                // 1024
    int blocks = (nrows + rows_per_block - 1) / rows_per_block;   // 1024
    mlp_mfma_final<<<blocks, NTHREADS, 0, stream>>>(
        x,
        (const float*)d_in[1],  (const float*)d_in[2],
        (const float*)d_in[3],  (const float*)d_in[4],
        (const float*)d_in[5],  (const float*)d_in[6],
        (const float*)d_in[7],  (const float*)d_in[8],
        (const float*)d_in[9],  (const float*)d_in[10],
        (const float*)d_in[11], (const float*)d_in[12],
        (const float*)d_in[13], (const float*)d_in[14],
        (float*)d_out, nrows);
}